// Round 11
// baseline (26.825 us; speedup 1.0000x reference)
//
#include <hip/hip_runtime.h>
#include <math.h>

#define NN 20
#define ED 4
#define XROW 160
#define NC 80
#define NKT 5
#define NNT 5
#define FRAG_BYTES (NKT * NNT * 64 * 16)     // 25600
#define THREADS 512
#define ROWS_PER_WAVE 16
#define CHUNK_ROWS 128                       // 8 waves * 16 rows
#define TPB 4                                // chunks per wave (block covers 512 rows)
#define ROWS_PER_BLOCK (CHUNK_ROWS * TPB)    // 512

typedef __attribute__((ext_vector_type(8))) _Float16 half8;
typedef __attribute__((ext_vector_type(4))) float f32x4;
typedef __attribute__((ext_vector_type(4))) unsigned uint4v;

static __device__ __forceinline__ half8 cvt8(float4 a, float4 b) {
    uint4v u = (uint4v){
        __builtin_bit_cast(unsigned, __builtin_amdgcn_cvt_pkrtz(a.x, a.y)),
        __builtin_bit_cast(unsigned, __builtin_amdgcn_cvt_pkrtz(a.z, a.w)),
        __builtin_bit_cast(unsigned, __builtin_amdgcn_cvt_pkrtz(b.x, b.y)),
        __builtin_bit_cast(unsigned, __builtin_amdgcn_cvt_pkrtz(b.z, b.w))};
    return __builtin_bit_cast(half8, u);
}

// quad_perm DPP: xor1 = [1,0,3,2] = 0xB1 ; xor2 = [2,3,0,1] = 0x4E
static __device__ __forceinline__ float dpp_xor1(float v) {
    return __builtin_bit_cast(float,
        __builtin_amdgcn_mov_dpp(__builtin_bit_cast(int, v), 0xB1, 0xF, 0xF, true));
}
static __device__ __forceinline__ float dpp_xor2(float v) {
    return __builtin_bit_cast(float,
        __builtin_amdgcn_mov_dpp(__builtin_bit_cast(int, v), 0x4E, 0xF, 0xF, true));
}

struct Burst {
    float4 a0, b0, a1, b1, a2, b2, a3, b3, a4, b4;
};

static __device__ __forceinline__ Burst load_burst(const float* __restrict__ p) {
    Burst r;
    r.a0 = *(const float4*)(p);       r.b0 = *(const float4*)(p + 4);
    r.a1 = *(const float4*)(p + 32);  r.b1 = *(const float4*)(p + 36);
    r.a2 = *(const float4*)(p + 64);  r.b2 = *(const float4*)(p + 68);
    r.a3 = *(const float4*)(p + 96);  r.b3 = *(const float4*)(p + 100);
    r.a4 = *(const float4*)(p + 128); r.b4 = *(const float4*)(p + 132);
    return r;
}

__global__ __launch_bounds__(THREADS, 2) void rgcn_fused(
        const float* __restrict__ x,
        const float* __restrict__ e,
        const float* __restrict__ gate_w,
        const float* __restrict__ gate_b,
        const float* __restrict__ upd_w,
        const float* __restrict__ upd_b,
        const float* __restrict__ lin_w,
        const float* __restrict__ lin_b,
        float* __restrict__ y) {
    __shared__ __align__(16) char fragmem[FRAG_BYTES];
    __shared__ float sbias[NC];
    __shared__ float el[80];
    __shared__ float sA[400];
    __shared__ float wself[640];
    __shared__ float wagg[640];

    const int t = threadIdx.x;
    const int l = t & 63;
    const int w = t >> 6;

    const size_t base = (size_t)blockIdx.x * ROWS_PER_BLOCK + (size_t)w * ROWS_PER_WAVE;
    // chunk c covers rows base + c*CHUNK_ROWS .. +16
    const float* xp = x + (base + (l & 15)) * XROW + ((l >> 4) << 3);
    const size_t xstep = (size_t)CHUNK_ROWS * XROW;

    // ---- burst 0 issued first; setup hides its latency ----
    Burst cur = load_burst(xp);

    // ---- setup: once per CU (grid == 1 block/CU) ----
    if (t < NN * ED) el[t] = e[t];
    __syncthreads();

    if (t < 400) {
        int nn = t / 20, mm = t - (t / 20) * 20;
        float d = 0.f;
        #pragma unroll
        for (int j = 0; j < ED; ++j) d += el[nn * ED + j] * el[mm * ED + j];
        sA[t] = fmaxf(d, 0.f);
    }
    #pragma unroll
    for (int idx = t; idx < 1280; idx += THREADS) {
        int sel = idx >= 640;
        int rem = sel ? idx - 640 : idx;
        int c = rem >> 3, i = rem & 7;
        int n = c >> 2, ro = c & 3;
        float v = 0.f;
        if (ro < 2) {
            int o = 2 + ro;
            #pragma unroll
            for (int d = 0; d < ED; ++d) v += el[n * ED + d] * gate_w[d * 80 + sel * 40 + i * 4 + o];
        } else {
            int o = ro - 2;
            #pragma unroll
            for (int d = 0; d < ED; ++d) v += el[n * ED + d] * upd_w[d * 40 + sel * 20 + i * 2 + o];
        }
        (sel ? wagg : wself)[rem] = v;
    }
    if (t < NC) {
        int n = t >> 2, ro = t & 3;
        float b = 0.f;
        #pragma unroll
        for (int d = 0; d < ED; ++d)
            b += el[n * ED + d] * (ro < 2 ? gate_b[d * 4 + 2 + ro] : upd_b[d * 2 + ro - 2]);
        sbias[t] = b;
    }
    __syncthreads();

    // ---- wave-parallel softmax: wave w handles rows w, w+8, w+16 ----
    {
        #pragma unroll
        for (int rep = 0; rep < 3; ++rep) {
            int r = w + rep * 8;
            if (r < NN) {
                float v = (l < NN) ? sA[r * 20 + l] : -1e30f;
                float mx = v;
                #pragma unroll
                for (int s = 32; s >= 1; s >>= 1) mx = fmaxf(mx, __shfl_xor(mx, s));
                float ex = (l < NN) ? __expf(v - mx) : 0.f;
                float sum = ex;
                #pragma unroll
                for (int s = 32; s >= 1; s >>= 1) sum += __shfl_xor(sum, s);
                if (l < NN) sA[r * 20 + l] = ex / sum;
            }
        }
    }
    __syncthreads();

    // ---- build fp16 B-fragments in LDS ----
    {
        half8* frag = (half8*)fragmem;
        for (int tile = w; tile < NKT * NNT; tile += 8) {
            int kt = tile / 5, nt = tile - kt * 5;
            int cc = nt * 16 + (l & 15);
            int nn = cc >> 2;
            int mm = kt * 4 + (l >> 4);
            float anm = sA[nn * 20 + mm];
            float4 wg0 = *(const float4*)&wagg[cc * 8];
            float4 wg1 = *(const float4*)&wagg[cc * 8 + 4];
            float v0 = anm * wg0.x, v1 = anm * wg0.y, v2 = anm * wg0.z, v3 = anm * wg0.w;
            float v4 = anm * wg1.x, v5 = anm * wg1.y, v6 = anm * wg1.z, v7 = anm * wg1.w;
            if (nn == mm) {
                float4 ws0 = *(const float4*)&wself[cc * 8];
                float4 ws1 = *(const float4*)&wself[cc * 8 + 4];
                v0 += ws0.x; v1 += ws0.y; v2 += ws0.z; v3 += ws0.w;
                v4 += ws1.x; v5 += ws1.y; v6 += ws1.z; v7 += ws1.w;
            }
            half8 hv;
            hv[0] = (_Float16)v0; hv[1] = (_Float16)v1; hv[2] = (_Float16)v2; hv[3] = (_Float16)v3;
            hv[4] = (_Float16)v4; hv[5] = (_Float16)v5; hv[6] = (_Float16)v6; hv[7] = (_Float16)v7;
            frag[tile * 64 + l] = hv;
        }
    }
    __syncthreads();

    const half8* frag = (const half8*)fragmem;
    const float lw0 = lin_w[0], lw1 = lin_w[1], lb = lin_b[0];
    const int ro = l & 3;
    const bool isR = ro < 2;
    const float myw = (ro & 1) ? lw1 : lw0;

    #define STEP(XA, XB, KT, ACC)                                                   \
    {                                                                               \
        half8 a = cvt8(XA, XB);                                                     \
        _Pragma("unroll")                                                           \
        for (int nt = 0; nt < NNT; ++nt) {                                          \
            half8 bh = frag[((KT) * NNT + nt) * 64 + l];                            \
            ACC[nt] = __builtin_amdgcn_mfma_f32_16x16x32_f16(a, bh, ACC[nt], 0, 0, 0); \
        }                                                                           \
    }

    #define COMPUTE(U, ROW0)                                                        \
    {                                                                               \
        f32x4 acc[NNT];                                                             \
        _Pragma("unroll")                                                           \
        for (int nt = 0; nt < NNT; ++nt) {                                          \
            float b = sbias[nt * 16 + (l & 15)];                                    \
            acc[nt] = (f32x4){b, b, b, b};                                          \
        }                                                                           \
        STEP(U.a0, U.b0, 0, acc)                                                    \
        STEP(U.a1, U.b1, 1, acc)                                                    \
        STEP(U.a2, U.b2, 2, acc)                                                    \
        STEP(U.a3, U.b3, 3, acc)                                                    \
        STEP(U.a4, U.b4, 4, acc)                                                    \
        const size_t rowb = (ROW0) + ((l >> 4) << 2) + ro;                          \
        _Pragma("unroll")                                                           \
        for (int nt = 0; nt < NNT; ++nt) {                                          \
            const int n = nt * 4 + ((l & 15) >> 2);                                 \
            float ysel = 0.f;                                                       \
            _Pragma("unroll")                                                       \
            for (int q = 0; q < 4; ++q) {                                           \
                float pre = acc[nt][q];                                             \
                float term;                                                         \
                if (isR) term = __builtin_amdgcn_rcpf(1.f + __expf(pre));           \
                else     term = 1.f - 2.f * __builtin_amdgcn_rcpf(__expf(2.f * pre) + 1.f); \
                float other = dpp_xor2(term);                                       \
                float h = term * other;                                             \
                float s = fmaxf(h, 0.f) * myw;                                      \
                float yq = s + dpp_xor1(s) + lb;                                    \
                if (q == ro) ysel = yq;                                             \
            }                                                                       \
            y[rowb * NN + n] = ysel;                                                \
        }                                                                           \
    }

    // ---- rolling 1-deep pipeline over 4 chunks ----
    Burst nxt = load_burst(xp + xstep);
    COMPUTE(cur, base)
    cur = nxt;
    nxt = load_burst(xp + 2 * xstep);
    COMPUTE(cur, base + CHUNK_ROWS)
    cur = nxt;
    nxt = load_burst(xp + 3 * xstep);
    COMPUTE(cur, base + 2 * CHUNK_ROWS)
    COMPUTE(nxt, base + 3 * CHUNK_ROWS)

    #undef STEP
    #undef COMPUTE
}

extern "C" void kernel_launch(void* const* d_in, const int* in_sizes, int n_in,
                              void* d_out, int out_size, void* d_ws, size_t ws_size,
                              hipStream_t stream) {
    const float* x      = (const float*)d_in[0];
    const float* e      = (const float*)d_in[1];
    const float* gate_w = (const float*)d_in[2];
    const float* gate_b = (const float*)d_in[3];
    const float* upd_w  = (const float*)d_in[4];
    const float* upd_b  = (const float*)d_in[5];
    const float* lin_w  = (const float*)d_in[6];
    const float* lin_b  = (const float*)d_in[7];
    float* y = (float*)d_out;

    const int Bn = in_sizes[0] / XROW;           // 131072
    const int nblocks = Bn / ROWS_PER_BLOCK;     // 256

    rgcn_fused<<<nblocks, THREADS, 0, stream>>>(x, e, gate_w, gate_b,
                                                upd_w, upd_b, lin_w, lin_b, y);
}

// Round 12
// 25.432 us; speedup vs baseline: 1.0548x; 1.0548x over previous
//
#include <hip/hip_runtime.h>
#include <math.h>

#define NN 20
#define ED 4
#define XROW 160
#define NC 80
#define NKT 5
#define NNT 5
#define FRAG_BYTES (NKT * NNT * 64 * 16)     // 25600
#define THREADS 512
#define ROWS_PER_WAVE 16
#define ROWS_PER_BLOCK 128                   // 8 waves * 16 rows
#define TPB 2                                // tiles per persistent block

typedef __attribute__((ext_vector_type(8))) _Float16 half8;
typedef __attribute__((ext_vector_type(4))) float f32x4;
typedef __attribute__((ext_vector_type(4))) unsigned uint4v;

static __device__ __forceinline__ half8 cvt8(float4 a, float4 b) {
    uint4v u = (uint4v){
        __builtin_bit_cast(unsigned, __builtin_amdgcn_cvt_pkrtz(a.x, a.y)),
        __builtin_bit_cast(unsigned, __builtin_amdgcn_cvt_pkrtz(a.z, a.w)),
        __builtin_bit_cast(unsigned, __builtin_amdgcn_cvt_pkrtz(b.x, b.y)),
        __builtin_bit_cast(unsigned, __builtin_amdgcn_cvt_pkrtz(b.z, b.w))};
    return __builtin_bit_cast(half8, u);
}

// quad_perm DPP: xor1 = [1,0,3,2] = 0xB1 ; xor2 = [2,3,0,1] = 0x4E
static __device__ __forceinline__ float dpp_xor1(float v) {
    return __builtin_bit_cast(float,
        __builtin_amdgcn_mov_dpp(__builtin_bit_cast(int, v), 0xB1, 0xF, 0xF, true));
}
static __device__ __forceinline__ float dpp_xor2(float v) {
    return __builtin_bit_cast(float,
        __builtin_amdgcn_mov_dpp(__builtin_bit_cast(int, v), 0x4E, 0xF, 0xF, true));
}

struct Burst {
    float4 a0, b0, a1, b1, a2, b2, a3, b3, a4, b4;
};

// sector-optimal: lane (g = l>>4) takes cols [g*4, g*4+4) and [16+g*4, 16+g*4+4)
// of each 32-col k-tile -> a-load covers one 64B sector per row, b the next.
static __device__ __forceinline__ Burst load_burst(const float* __restrict__ p) {
    Burst r;
    r.a0 = *(const float4*)(p);        r.b0 = *(const float4*)(p + 16);
    r.a1 = *(const float4*)(p + 32);   r.b1 = *(const float4*)(p + 48);
    r.a2 = *(const float4*)(p + 64);   r.b2 = *(const float4*)(p + 80);
    r.a3 = *(const float4*)(p + 96);   r.b3 = *(const float4*)(p + 112);
    r.a4 = *(const float4*)(p + 128);  r.b4 = *(const float4*)(p + 144);
    return r;
}

__global__ __launch_bounds__(THREADS, 4) void rgcn_fused(
        const float* __restrict__ x,
        const float* __restrict__ e,
        const float* __restrict__ gate_w,
        const float* __restrict__ gate_b,
        const float* __restrict__ upd_w,
        const float* __restrict__ upd_b,
        const float* __restrict__ lin_w,
        const float* __restrict__ lin_b,
        float* __restrict__ y) {
    __shared__ __align__(16) char fragmem[FRAG_BYTES];
    __shared__ float sbias[NC];
    __shared__ float el[80];
    __shared__ float sA[400];
    __shared__ float wself[640];
    __shared__ float wagg[640];

    const int t = threadIdx.x;
    const int l = t & 63;
    const int w = t >> 6;

    const size_t rowA = ((size_t)blockIdx.x * TPB + 0) * ROWS_PER_BLOCK + (size_t)w * ROWS_PER_WAVE;
    const size_t rowB = ((size_t)blockIdx.x * TPB + 1) * ROWS_PER_BLOCK + (size_t)w * ROWS_PER_WAVE;
    // per-lane base: row (l&15), col group g*4  (g = l>>4)
    const float* xpA = x + (rowA + (l & 15)) * XROW + ((l >> 4) << 2);
    const float* xpB = x + (rowB + (l & 15)) * XROW + ((l >> 4) << 2);

    // ---- burst A: issued first, latency hidden under setup ----
    Burst bA = load_burst(xpA);

    // ---- setup (once per block, amortized over 2 tiles) ----
    if (t < NN * ED) el[t] = e[t];
    __syncthreads();

    if (t < 400) {
        int nn = t / 20, mm = t - (t / 20) * 20;
        float d = 0.f;
        #pragma unroll
        for (int j = 0; j < ED; ++j) d += el[nn * ED + j] * el[mm * ED + j];
        sA[t] = fmaxf(d, 0.f);
    }
    #pragma unroll
    for (int idx = t; idx < 1280; idx += THREADS) {
        int sel = idx >= 640;
        int rem = sel ? idx - 640 : idx;
        int c = rem >> 3, i = rem & 7;
        int n = c >> 2, ro = c & 3;
        float v = 0.f;
        if (ro < 2) {
            int o = 2 + ro;
            #pragma unroll
            for (int d = 0; d < ED; ++d) v += el[n * ED + d] * gate_w[d * 80 + sel * 40 + i * 4 + o];
        } else {
            int o = ro - 2;
            #pragma unroll
            for (int d = 0; d < ED; ++d) v += el[n * ED + d] * upd_w[d * 40 + sel * 20 + i * 2 + o];
        }
        (sel ? wagg : wself)[rem] = v;
    }
    if (t < NC) {
        int n = t >> 2, ro = t & 3;
        float b = 0.f;
        #pragma unroll
        for (int d = 0; d < ED; ++d)
            b += el[n * ED + d] * (ro < 2 ? gate_b[d * 4 + 2 + ro] : upd_b[d * 2 + ro - 2]);
        sbias[t] = b;
    }
    __syncthreads();

    if (t < NN) {
        float mx = -1e30f;
        for (int m = 0; m < NN; ++m) mx = fmaxf(mx, sA[t * 20 + m]);
        float ex[NN]; float sum = 0.f;
        for (int m = 0; m < NN; ++m) { ex[m] = __expf(sA[t * 20 + m] - mx); sum += ex[m]; }
        float inv = 1.f / sum;
        for (int m = 0; m < NN; ++m) sA[t * 20 + m] = ex[m] * inv;
    }
    __syncthreads();

    // ---- build fp16 B-fragments with the SAME k-slot permutation as the loads ----
    {
        half8* frag = (half8*)fragmem;
        const int gg = l >> 4;
        for (int tile = w; tile < NKT * NNT; tile += 8) {
            int kt = tile / 5, nt = tile - kt * 5;
            int cc = nt * 16 + (l & 15);
            int nn = cc >> 2;
            half8 hv;
            #pragma unroll
            for (int j = 0; j < 8; ++j) {
                int kk = (j < 4) ? (gg * 4 + j) : (16 + gg * 4 + (j - 4));
                int k = kt * 32 + kk;
                int m = k >> 3, i = k & 7;
                float val = sA[nn * 20 + m] * wagg[cc * 8 + i]
                          + (nn == m ? wself[cc * 8 + i] : 0.f);
                hv[j] = (_Float16)val;
            }
            frag[tile * 64 + l] = hv;
        }
    }
    __syncthreads();

    const half8* frag = (const half8*)fragmem;
    const float lw0 = lin_w[0], lw1 = lin_w[1], lb = lin_b[0];
    const int ro = l & 3;
    const bool isR = ro < 2;
    const float myw = (ro & 1) ? lw1 : lw0;

    // ---- burst B issued NOW: latency hides under tile A's MFMA+epilogue ----
    Burst bB = load_burst(xpB);

    #define STEP(XA, XB, KT, ACC)                                                   \
    {                                                                               \
        half8 a = cvt8(XA, XB);                                                     \
        _Pragma("unroll")                                                           \
        for (int nt = 0; nt < NNT; ++nt) {                                          \
            half8 bh = frag[((KT) * NNT + nt) * 64 + l];                            \
            ACC[nt] = __builtin_amdgcn_mfma_f32_16x16x32_f16(a, bh, ACC[nt], 0, 0, 0); \
        }                                                                           \
    }

    #define EPILOGUE(ACC, ROW0)                                                     \
    {                                                                               \
        const size_t rowb = (ROW0) + ((l >> 4) << 2) + ro;                          \
        _Pragma("unroll")                                                           \
        for (int nt = 0; nt < NNT; ++nt) {                                          \
            const int n = nt * 4 + ((l & 15) >> 2);                                 \
            float ysel = 0.f;                                                       \
            _Pragma("unroll")                                                       \
            for (int q = 0; q < 4; ++q) {                                           \
                float pre = ACC[nt][q];                                             \
                float term;                                                         \
                if (isR) term = __builtin_amdgcn_rcpf(1.f + __expf(pre));           \
                else     term = 1.f - 2.f * __builtin_amdgcn_rcpf(__expf(2.f * pre) + 1.f); \
                float other = dpp_xor2(term);                                       \
                float h = term * other;                                             \
                float s = fmaxf(h, 0.f) * myw;                                      \
                float yq = s + dpp_xor1(s) + lb;                                    \
                if (q == ro) ysel = yq;                                             \
            }                                                                       \
            y[rowb * NN + n] = ysel;                                                \
        }                                                                           \
    }

    // ---- tile A ----
    {
        f32x4 accA[NNT];
        #pragma unroll
        for (int nt = 0; nt < NNT; ++nt) {
            float b = sbias[nt * 16 + (l & 15)];
            accA[nt] = (f32x4){b, b, b, b};
        }
        STEP(bA.a0, bA.b0, 0, accA)
        STEP(bA.a1, bA.b1, 1, accA)
        STEP(bA.a2, bA.b2, 2, accA)
        STEP(bA.a3, bA.b3, 3, accA)
        STEP(bA.a4, bA.b4, 4, accA)
        EPILOGUE(accA, rowA)
    }

    // ---- tile B ----
    {
        f32x4 accB[NNT];
        #pragma unroll
        for (int nt = 0; nt < NNT; ++nt) {
            float b = sbias[nt * 16 + (l & 15)];
            accB[nt] = (f32x4){b, b, b, b};
        }
        STEP(bB.a0, bB.b0, 0, accB)
        STEP(bB.a1, bB.b1, 1, accB)
        STEP(bB.a2, bB.b2, 2, accB)
        STEP(bB.a3, bB.b3, 3, accB)
        STEP(bB.a4, bB.b4, 4, accB)
        EPILOGUE(accB, rowB)
    }
    #undef STEP
    #undef EPILOGUE
}

extern "C" void kernel_launch(void* const* d_in, const int* in_sizes, int n_in,
                              void* d_out, int out_size, void* d_ws, size_t ws_size,
                              hipStream_t stream) {
    const float* x      = (const float*)d_in[0];
    const float* e      = (const float*)d_in[1];
    const float* gate_w = (const float*)d_in[2];
    const float* gate_b = (const float*)d_in[3];
    const float* upd_w  = (const float*)d_in[4];
    const float* upd_b  = (const float*)d_in[5];
    const float* lin_w  = (const float*)d_in[6];
    const float* lin_b  = (const float*)d_in[7];
    float* y = (float*)d_out;

    const int Bn = in_sizes[0] / XROW;                     // 131072
    const int nblocks = Bn / (ROWS_PER_BLOCK * TPB);       // 512

    rgcn_fused<<<nblocks, THREADS, 0, stream>>>(x, e, gate_w, gate_b,
                                                upd_w, upd_b, lin_w, lin_b, y);
}

// Round 13
// 25.198 us; speedup vs baseline: 1.0646x; 1.0093x over previous
//
#include <hip/hip_runtime.h>
#include <math.h>

#define NN 20
#define ED 4
#define XROW 160
#define NC 80
#define NKT 5
#define NNT 5
#define FRAG_BYTES (NKT * NNT * 64 * 16)     // 25600
#define THREADS 512
#define ROWS_PER_WAVE 16
#define ROWS_PER_BLOCK 128                   // 8 waves * 16 rows
#define TPB 2                                // tiles per persistent block

typedef __attribute__((ext_vector_type(8))) _Float16 half8;
typedef __attribute__((ext_vector_type(4))) float f32x4;
typedef __attribute__((ext_vector_type(4))) unsigned uint4v;

static __device__ __forceinline__ half8 cvt8(float4 a, float4 b) {
    uint4v u = (uint4v){
        __builtin_bit_cast(unsigned, __builtin_amdgcn_cvt_pkrtz(a.x, a.y)),
        __builtin_bit_cast(unsigned, __builtin_amdgcn_cvt_pkrtz(a.z, a.w)),
        __builtin_bit_cast(unsigned, __builtin_amdgcn_cvt_pkrtz(b.x, b.y)),
        __builtin_bit_cast(unsigned, __builtin_amdgcn_cvt_pkrtz(b.z, b.w))};
    return __builtin_bit_cast(half8, u);
}

// quad_perm DPP: xor1 = [1,0,3,2] = 0xB1 ; xor2 = [2,3,0,1] = 0x4E
static __device__ __forceinline__ float dpp_xor1(float v) {
    return __builtin_bit_cast(float,
        __builtin_amdgcn_mov_dpp(__builtin_bit_cast(int, v), 0xB1, 0xF, 0xF, true));
}
static __device__ __forceinline__ float dpp_xor2(float v) {
    return __builtin_bit_cast(float,
        __builtin_amdgcn_mov_dpp(__builtin_bit_cast(int, v), 0x4E, 0xF, 0xF, true));
}

// LDS-only barrier: orders ds ops, does NOT drain vmcnt (x bursts stay in flight)
#define BARRIER_NODRAIN()                                   \
    do {                                                    \
        asm volatile("s_waitcnt lgkmcnt(0)" ::: "memory");  \
        __builtin_amdgcn_s_barrier();                       \
        __builtin_amdgcn_sched_barrier(0);                  \
    } while (0)

struct Burst {
    float4 a0, b0, a1, b1, a2, b2, a3, b3, a4, b4;
};

static __device__ __forceinline__ Burst load_burst(const float* __restrict__ p) {
    Burst r;
    r.a0 = *(const float4*)(p);       r.b0 = *(const float4*)(p + 4);
    r.a1 = *(const float4*)(p + 32);  r.b1 = *(const float4*)(p + 36);
    r.a2 = *(const float4*)(p + 64);  r.b2 = *(const float4*)(p + 68);
    r.a3 = *(const float4*)(p + 96);  r.b3 = *(const float4*)(p + 100);
    r.a4 = *(const float4*)(p + 128); r.b4 = *(const float4*)(p + 132);
    return r;
}

__global__ __launch_bounds__(THREADS, 4) void rgcn_fused(
        const float* __restrict__ x,
        const float* __restrict__ e,
        const float* __restrict__ gate_w,
        const float* __restrict__ gate_b,
        const float* __restrict__ upd_w,
        const float* __restrict__ upd_b,
        const float* __restrict__ lin_w,
        const float* __restrict__ lin_b,
        float* __restrict__ y) {
    __shared__ __align__(16) char fragmem[FRAG_BYTES];
    __shared__ float sbias[NC];
    __shared__ float el[80];
    __shared__ float sA[400];
    __shared__ float wself[640];
    __shared__ float wagg[640];

    const int t = threadIdx.x;
    const int l = t & 63;
    const int w = t >> 6;

    const size_t rowA = ((size_t)blockIdx.x * TPB + 0) * ROWS_PER_BLOCK + (size_t)w * ROWS_PER_WAVE;
    const size_t rowB = ((size_t)blockIdx.x * TPB + 1) * ROWS_PER_BLOCK + (size_t)w * ROWS_PER_WAVE;
    const float* xpA = x + (rowA + (l & 15)) * XROW + ((l >> 4) << 3);
    const float* xpB = x + (rowB + (l & 15)) * XROW + ((l >> 4) << 3);

    // ---- scalar consts (SMEM path, lgkmcnt) ----
    const float lw0 = lin_w[0], lw1 = lin_w[1], lb = lin_b[0];

    // ---- prefetch e (issued first -> retires first) ----
    float ev = 0.f;
    if (t < NN * ED) ev = e[t];

    // ---- prefetch folded-weight operands into regs: rem1 = t, rem2 = t+512 ----
    float q0a[ED], q1a[ED];
    {
        int c = t >> 3, i = t & 7, ro = c & 3;
        const float* b0; const float* b1; int st;
        if (ro < 2) { b0 = gate_w + i * 4 + 2 + ro; b1 = b0 + 40; st = 80; }
        else        { b0 = upd_w  + i * 2 + ro - 2; b1 = b0 + 20; st = 40; }
        #pragma unroll
        for (int d = 0; d < ED; ++d) { q0a[d] = b0[d * st]; q1a[d] = b1[d * st]; }
    }
    float q0b[ED], q1b[ED];
    if (t < 128) {
        int rem = t + 512;
        int c = rem >> 3, i = rem & 7, ro = c & 3;
        const float* b0; const float* b1; int st;
        if (ro < 2) { b0 = gate_w + i * 4 + 2 + ro; b1 = b0 + 40; st = 80; }
        else        { b0 = upd_w  + i * 2 + ro - 2; b1 = b0 + 20; st = 40; }
        #pragma unroll
        for (int d = 0; d < ED; ++d) { q0b[d] = b0[d * st]; q1b[d] = b1[d * st]; }
    }
    float pb[ED];
    if (t < NC) {
        int rb = t & 3;
        #pragma unroll
        for (int d = 0; d < ED; ++d)
            pb[d] = (rb < 2) ? gate_b[d * 4 + 2 + rb] : upd_b[d * 2 + rb - 2];
    }

    // ---- BOTH x bursts issued now: 20 loads/lane in flight through all of setup ----
    Burst bA = load_burst(xpA);
    Burst bB = load_burst(xpB);
    __builtin_amdgcn_sched_barrier(0);

    if (t < NN * ED) el[t] = ev;     // waits only for e (oldest load), bursts stay out
    BARRIER_NODRAIN();

    // ---- scores (LDS) + folded weights (regs) ----
    if (t < 400) {
        int nn = t / 20, mm = t - (t / 20) * 20;
        float d = 0.f;
        #pragma unroll
        for (int j = 0; j < ED; ++j) d += el[nn * ED + j] * el[mm * ED + j];
        sA[t] = fmaxf(d, 0.f);
    }
    {
        int n1 = t >> 5;
        float vs = 0.f, va = 0.f;
        #pragma unroll
        for (int d = 0; d < ED; ++d) {
            float evd = el[n1 * ED + d];
            vs += evd * q0a[d];
            va += evd * q1a[d];
        }
        wself[t] = vs;
        wagg[t]  = va;
    }
    if (t < 128) {
        int rem = t + 512, n2 = rem >> 5;
        float vs = 0.f, va = 0.f;
        #pragma unroll
        for (int d = 0; d < ED; ++d) {
            float evd = el[n2 * ED + d];
            vs += evd * q0b[d];
            va += evd * q1b[d];
        }
        wself[rem] = vs;
        wagg[rem]  = va;
    }
    if (t < NC) {
        float b = 0.f;
        #pragma unroll
        for (int d = 0; d < ED; ++d) b += el[(t >> 2) * ED + d] * pb[d];
        sbias[t] = b;
    }
    BARRIER_NODRAIN();

    // ---- row softmax in place ----
    if (t < NN) {
        float mx = -1e30f;
        for (int m = 0; m < NN; ++m) mx = fmaxf(mx, sA[t * 20 + m]);
        float ex[NN]; float sum = 0.f;
        for (int m = 0; m < NN; ++m) { ex[m] = __expf(sA[t * 20 + m] - mx); sum += ex[m]; }
        float inv = 1.f / sum;
        for (int m = 0; m < NN; ++m) sA[t * 20 + m] = ex[m] * inv;
    }
    BARRIER_NODRAIN();

    // ---- build fp16 B-fragments ----
    {
        half8* frag = (half8*)fragmem;
        for (int tile = w; tile < NKT * NNT; tile += 8) {
            int kt = tile / 5, nt = tile - kt * 5;
            int cc = nt * 16 + (l & 15);
            int nn = cc >> 2;
            int mm = kt * 4 + (l >> 4);
            float anm = sA[nn * 20 + mm];
            float4 wg0 = *(const float4*)&wagg[cc * 8];
            float4 wg1 = *(const float4*)&wagg[cc * 8 + 4];
            float v0 = anm * wg0.x, v1 = anm * wg0.y, v2 = anm * wg0.z, v3 = anm * wg0.w;
            float v4 = anm * wg1.x, v5 = anm * wg1.y, v6 = anm * wg1.z, v7 = anm * wg1.w;
            if (nn == mm) {
                float4 ws0 = *(const float4*)&wself[cc * 8];
                float4 ws1 = *(const float4*)&wself[cc * 8 + 4];
                v0 += ws0.x; v1 += ws0.y; v2 += ws0.z; v3 += ws0.w;
                v4 += ws1.x; v5 += ws1.y; v6 += ws1.z; v7 += ws1.w;
            }
            half8 hv;
            hv[0] = (_Float16)v0; hv[1] = (_Float16)v1; hv[2] = (_Float16)v2; hv[3] = (_Float16)v3;
            hv[4] = (_Float16)v4; hv[5] = (_Float16)v5; hv[6] = (_Float16)v6; hv[7] = (_Float16)v7;
            frag[tile * 64 + l] = hv;
        }
    }
    BARRIER_NODRAIN();

    const half8* frag = (const half8*)fragmem;
    const int ro = l & 3;
    const bool isR = ro < 2;
    const float myw = (ro & 1) ? lw1 : lw0;

    #define STEP(XA, XB, KT, ACC)                                                   \
    {                                                                               \
        half8 a = cvt8(XA, XB);                                                     \
        _Pragma("unroll")                                                           \
        for (int nt = 0; nt < NNT; ++nt) {                                          \
            half8 bh = frag[((KT) * NNT + nt) * 64 + l];                            \
            ACC[nt] = __builtin_amdgcn_mfma_f32_16x16x32_f16(a, bh, ACC[nt], 0, 0, 0); \
        }                                                                           \
    }

    #define EPILOGUE(ACC, ROW0)                                                     \
    {                                                                               \
        const size_t rowb = (ROW0) + ((l >> 4) << 2) + ro;                          \
        _Pragma("unroll")                                                           \
        for (int nt = 0; nt < NNT; ++nt) {                                          \
            const int n = nt * 4 + ((l & 15) >> 2);                                 \
            float ysel = 0.f;                                                       \
            _Pragma("unroll")                                                       \
            for (int q = 0; q < 4; ++q) {                                           \
                float pre = ACC[nt][q];                                             \
                float term;                                                         \
                if (isR) term = __builtin_amdgcn_rcpf(1.f + __expf(pre));           \
                else     term = 1.f - 2.f * __builtin_amdgcn_rcpf(__expf(2.f * pre) + 1.f); \
                float other = dpp_xor2(term);                                       \
                float h = term * other;                                             \
                float s = fmaxf(h, 0.f) * myw;                                      \
                float yq = s + dpp_xor1(s) + lb;                                    \
                if (q == ro) ysel = yq;                                             \
            }                                                                       \
            y[rowb * NN + n] = ysel;                                                \
        }                                                                           \
    }

    // ---- tile A (waits vmcnt for bA only; bB still in flight) ----
    {
        f32x4 accA[NNT];
        #pragma unroll
        for (int nt = 0; nt < NNT; ++nt) {
            float b = sbias[nt * 16 + (l & 15)];
            accA[nt] = (f32x4){b, b, b, b};
        }
        STEP(bA.a0, bA.b0, 0, accA)
        STEP(bA.a1, bA.b1, 1, accA)
        STEP(bA.a2, bA.b2, 2, accA)
        STEP(bA.a3, bA.b3, 3, accA)
        STEP(bA.a4, bA.b4, 4, accA)
        EPILOGUE(accA, rowA)
    }

    // ---- tile B ----
    {
        f32x4 accB[NNT];
        #pragma unroll
        for (int nt = 0; nt < NNT; ++nt) {
            float b = sbias[nt * 16 + (l & 15)];
            accB[nt] = (f32x4){b, b, b, b};
        }
        STEP(bB.a0, bB.b0, 0, accB)
        STEP(bB.a1, bB.b1, 1, accB)
        STEP(bB.a2, bB.b2, 2, accB)
        STEP(bB.a3, bB.b3, 3, accB)
        STEP(bB.a4, bB.b4, 4, accB)
        EPILOGUE(accB, rowB)
    }
    #undef STEP
    #undef EPILOGUE
}

extern "C" void kernel_launch(void* const* d_in, const int* in_sizes, int n_in,
                              void* d_out, int out_size, void* d_ws, size_t ws_size,
                              hipStream_t stream) {
    const float* x      = (const float*)d_in[0];
    const float* e      = (const float*)d_in[1];
    const float* gate_w = (const float*)d_in[2];
    const float* gate_b = (const float*)d_in[3];
    const float* upd_w  = (const float*)d_in[4];
    const float* upd_b  = (const float*)d_in[5];
    const float* lin_w  = (const float*)d_in[6];
    const float* lin_b  = (const float*)d_in[7];
    float* y = (float*)d_out;

    const int Bn = in_sizes[0] / XROW;                     // 131072
    const int nblocks = Bn / (ROWS_PER_BLOCK * TPB);       // 512

    rgcn_fused<<<nblocks, THREADS, 0, stream>>>(x, e, gate_w, gate_b,
                                                upd_w, upd_b, lin_w, lin_b, y);
}